// Round 1
// baseline (129.186 us; speedup 1.0000x reference)
//
#include <hip/hip_runtime.h>
#include <hip/hip_bf16.h>

#define N_NODES 8192
#define IN_F 128
#define OUT_F 64
#define ALPHA 0.2f
#define CAP 1024  // max edges per row (expected ~164, binomial max ~220)

// Kernel 1: h = x @ W  [N,64];  hi = h @ a[:64];  hj = h @ a[64:]
// Block: 256 threads = 4 waves; each wave owns one row at a time (lane = out feature).
// 32 rows per block -> grid 256.
__global__ __launch_bounds__(256) void gat_h(
    const float* __restrict__ x, const float* __restrict__ W,
    const float* __restrict__ a, float* __restrict__ h,
    float* __restrict__ hi, float* __restrict__ hj) {
  __shared__ float sW[IN_F * OUT_F];  // 32 KB
  int tid = threadIdx.x;
  for (int i = tid; i < IN_F * OUT_F; i += 256) sW[i] = W[i];
  __syncthreads();

  int f = tid & 63;        // output feature (lane)
  int rloc = tid >> 6;     // wave id 0..3
  float a1 = a[f], a2 = a[OUT_F + f];
  int row0 = blockIdx.x * 32;

  for (int rr = 0; rr < 8; ++rr) {
    int row = row0 + rr * 4 + rloc;
    const float4* xr = (const float4*)(x + (size_t)row * IN_F);
    float acc = 0.f;
#pragma unroll
    for (int k4 = 0; k4 < IN_F / 4; ++k4) {
      float4 xv = xr[k4];  // wave-uniform broadcast load
      acc = fmaf(xv.x, sW[(k4 * 4 + 0) * 64 + f], acc);
      acc = fmaf(xv.y, sW[(k4 * 4 + 1) * 64 + f], acc);
      acc = fmaf(xv.z, sW[(k4 * 4 + 2) * 64 + f], acc);
      acc = fmaf(xv.w, sW[(k4 * 4 + 3) * 64 + f], acc);
    }
    h[(size_t)row * 64 + f] = acc;
    float vi = acc * a1, vj = acc * a2;
#pragma unroll
    for (int o = 32; o >= 1; o >>= 1) {
      vi += __shfl_xor(vi, o);
      vj += __shfl_xor(vj, o);
    }
    if (f == 0) { hi[row] = vi; hj[row] = vj; }
  }
}

// Kernel 2: one block (256 threads) per row.
// Scan adj row (float4 coalesced), ballot-compact edge indices into LDS,
// softmax over edge logits, gather-accumulate h[j], ELU, write row of out.
__global__ __launch_bounds__(256) void gat_row(
    const float* __restrict__ adj, const float* __restrict__ h,
    const float* __restrict__ hi, const float* __restrict__ hj,
    float* __restrict__ out) {
  __shared__ int s_idx[CAP];
  __shared__ float s_w[CAP];
  __shared__ int s_cnt;
  __shared__ float s_redA[4];
  __shared__ float s_redB[4];
  __shared__ float s_part[4][64];

  int tid = threadIdx.x;
  int lane = tid & 63;
  int wid = tid >> 6;
  int row = blockIdx.x;

  if (tid == 0) s_cnt = 0;
  __syncthreads();

  // --- edge compaction (ballot + one LDS atomic per wave per predicate) ---
  const float4* arow = (const float4*)(adj + (size_t)row * N_NODES);
  auto compact = [&](bool pred, int j) {
    unsigned long long m = __ballot(pred);
    int tot = __popcll(m);
    int base = 0;
    if (lane == 0 && tot) base = atomicAdd(&s_cnt, tot);
    base = __shfl(base, 0);
    if (pred) {
      int pos = base + __popcll(m & ((1ull << lane) - 1ull));
      if (pos < CAP) s_idx[pos] = j;
    }
  };
#pragma unroll
  for (int it = 0; it < N_NODES / 4 / 256; ++it) {
    int vi = tid + it * 256;
    float4 v = arow[vi];
    int jb = vi * 4;
    compact(v.x > 0.f, jb + 0);
    compact(v.y > 0.f, jb + 1);
    compact(v.z > 0.f, jb + 2);
    compact(v.w > 0.f, jb + 3);
  }
  __syncthreads();
  int cnt = s_cnt;
  if (cnt > CAP) cnt = CAP;

  // --- logits + block max ---
  float hii = hi[row];
  float lmax = -1e30f;
  for (int e = tid; e < cnt; e += 256) {
    int j = s_idx[e];
    float l = hii + hj[j];
    l = (l > 0.f) ? l : ALPHA * l;  // leaky relu
    s_w[e] = l;
    lmax = fmaxf(lmax, l);
  }
#pragma unroll
  for (int o = 32; o >= 1; o >>= 1) lmax = fmaxf(lmax, __shfl_xor(lmax, o));
  if (lane == 0) s_redA[wid] = lmax;
  __syncthreads();
  float bmax = fmaxf(fmaxf(s_redA[0], s_redA[1]), fmaxf(s_redA[2], s_redA[3]));

  // --- exp + block sum ---
  float lsum = 0.f;
  for (int e = tid; e < cnt; e += 256) {
    float w = __expf(s_w[e] - bmax);
    s_w[e] = w;
    lsum += w;
  }
#pragma unroll
  for (int o = 32; o >= 1; o >>= 1) lsum += __shfl_xor(lsum, o);
  if (lane == 0) s_redB[wid] = lsum;
  __syncthreads();  // also covers s_w writes before the gather below
  float bsum = s_redB[0] + s_redB[1] + s_redB[2] + s_redB[3];

  // --- weighted gather of h: 4 edge-groups x 64 features ---
  int f = lane;       // feature
  int g = wid;        // edge group 0..3
  float acc = 0.f;
  for (int e = g; e < cnt; e += 4) {
    acc += s_w[e] * h[(size_t)s_idx[e] * 64 + f];
  }
  s_part[g][f] = acc;
  __syncthreads();
  if (tid < 64) {
    float v = s_part[0][f] + s_part[1][f] + s_part[2][f] + s_part[3][f];
    v /= bsum;
    v = (v > 0.f) ? v : expm1f(v);  // ELU
    out[(size_t)row * 64 + f] = v;
  }
}

extern "C" void kernel_launch(void* const* d_in, const int* in_sizes, int n_in,
                              void* d_out, int out_size, void* d_ws, size_t ws_size,
                              hipStream_t stream) {
  const float* x   = (const float*)d_in[0];  // [8192,128]
  const float* adj = (const float*)d_in[1];  // [8192,8192]
  const float* W   = (const float*)d_in[2];  // [128,64]
  const float* a   = (const float*)d_in[3];  // [128,1]
  float* out = (float*)d_out;                // [8192,64]

  float* h  = (float*)d_ws;                  // 8192*64
  float* hi = h + (size_t)N_NODES * OUT_F;   // 8192
  float* hj = hi + N_NODES;                  // 8192

  gat_h<<<N_NODES / 32, 256, 0, stream>>>(x, W, a, h, hi, hj);
  gat_row<<<N_NODES, 256, 0, stream>>>(adj, h, hi, hj, out);
}